// Round 1
// baseline (361.688 us; speedup 1.0000x reference)
//
#include <hip/hip_runtime.h>

// Butterfly network: 12 stages over rows of 4096 fp32.
// y[p] <- W[s][p][0]*y[p] + W[s][p][1]*y[p^d],  d = 1<<s, s = 0..11
//
// One block (256 thr) processes RPB=4 rows entirely on-chip:
//   layout 1 (p = 16t+i)            -> stages 0..3 in registers
//   layout 2 (p = hi*256 + 16j+lo)  -> stages 4..7 in registers
//   layout 3 (p = 256k + t)         -> stages 8..11 in registers, coalesced store
//
// LDS is 32 KB (float2[4096] = row-PAIR packed) so 5 blocks/CU fit
// (160 KB LDS / 32 KB), vs 2 blocks at the old 64 KB. Each transition runs
// twice (rows 0-1 then rows 2-3) with b64 LDS ops.
//
// Swizzle: position (P2,P1,P0) row-pair lives at float2 index
//     A2 = P2*256 + P0*16 + (P1 ^ P0)
// All four access patterns are bank-uniform (4 lanes per bank-pair = the
// throughput minimum for wave64 b64 ops):
//   T1 write (thread = [P2|P1], iter i=P0): A2 = hi*256 + i*16 + (lo^i)
//   T1 read  (thread = [P2|P0], iter j=P1): A2 = hi*256 + lo*16 + (j^lo)
//   T2 write (thread = [P2|P0], iter j=P1): same addresses as T1 read
//                                           -> thread-private, no barrier
//   T2 read  (thread = [P1|P0], iter k=P2): A2 = k*256 + lo*16 + (hi^lo)
// XOR terms land in ADDRESSES only; register indices stay compile-time.

constexpr int LROW = 4096;
constexpr int RPB  = 4;     // rows per block
constexpr int NBLK = 8192 / RPB;

__global__ __launch_bounds__(256, 5)
void butterfly12_kernel(const float* __restrict__ x,
                        const float* __restrict__ W,
                        float* __restrict__ out)
{
    __shared__ float2 lds[LROW];   // 32 KB -> 5 blocks/CU

    const int t  = threadIdx.x;
    const int hi = t >> 4;         // P2 in layouts 1,2 ; P1 in layout 3
    const int lo = t & 15;         // P1 in layout 1 ; P0 in layouts 2,3
    const size_t row0 = (size_t)blockIdx.x * RPB;

    float v[RPB][16];

    // ---- load: layout 1, p = 16t + i, 4 x float4 per row ----
    #pragma unroll
    for (int r = 0; r < RPB; ++r) {
        const float4* xr = reinterpret_cast<const float4*>(x + (row0 + r) * LROW);
        #pragma unroll
        for (int m = 0; m < 4; ++m) {
            const float4 q = xr[t * 4 + m];
            v[r][4*m+0] = q.x; v[r][4*m+1] = q.y;
            v[r][4*m+2] = q.z; v[r][4*m+3] = q.w;
        }
    }

    // ---- phase 1: stages 0..3, p = 16t + i ----
    #pragma unroll
    for (int b = 0; b < 4; ++b) {
        const int s = b;
        float2 ws[16];
        const float4* wq = reinterpret_cast<const float4*>(W + ((size_t)s * LROW + t * 16) * 2);
        #pragma unroll
        for (int m = 0; m < 8; ++m) {
            const float4 q = wq[m];
            ws[2*m]   = make_float2(q.x, q.y);
            ws[2*m+1] = make_float2(q.z, q.w);
        }
        const int dl = 1 << b;
        #pragma unroll
        for (int g = 0; g < 16; g += 2*dl)
            #pragma unroll
            for (int m = 0; m < dl; ++m) {
                const int a = g + m, c = a + dl;
                #pragma unroll
                for (int r = 0; r < RPB; ++r) {
                    const float va = v[r][a], vb = v[r][c];
                    v[r][a] = ws[a].x * va + ws[a].y * vb;
                    v[r][c] = ws[c].x * vb + ws[c].y * va;
                }
            }
    }

    // ---- transition 1 -> layout 2, row-pair at a time through 32 KB ----
    #pragma unroll
    for (int h = 0; h < 2; ++h) {
        if (h) __syncthreads();             // WAR: pair-0 reads done before overwrite
        #pragma unroll
        for (int i = 0; i < 16; ++i)
            lds[hi*256 + i*16 + (lo ^ i)] = make_float2(v[2*h][i], v[2*h+1][i]);
        __syncthreads();
        #pragma unroll
        for (int j = 0; j < 16; ++j) {
            const float2 q = lds[hi*256 + lo*16 + (j ^ lo)];
            v[2*h][j] = q.x; v[2*h+1][j] = q.y;
        }
    }

    // ---- phase 2: stages 4..7, p = hi*256 + 16j + lo ----
    #pragma unroll
    for (int b = 0; b < 4; ++b) {
        const int s = 4 + b;
        float2 ws[16];
        #pragma unroll
        for (int j = 0; j < 16; ++j)
            ws[j] = *reinterpret_cast<const float2*>(W + ((size_t)s * LROW + hi*256 + j*16 + lo) * 2);
        const int dl = 1 << b;
        #pragma unroll
        for (int g = 0; g < 16; g += 2*dl)
            #pragma unroll
            for (int m = 0; m < dl; ++m) {
                const int a = g + m, c = a + dl;
                #pragma unroll
                for (int r = 0; r < RPB; ++r) {
                    const float va = v[r][a], vb = v[r][c];
                    v[r][a] = ws[a].x * va + ws[a].y * vb;
                    v[r][c] = ws[c].x * vb + ws[c].y * va;
                }
            }
    }

    // ---- transition 2 -> layout 3, row-pair at a time ----
    // first write hits exactly the addresses this thread read in transition 1
    // (thread-private slot set => no barrier before it)
    #pragma unroll
    for (int h = 0; h < 2; ++h) {
        if (h) __syncthreads();
        #pragma unroll
        for (int j = 0; j < 16; ++j)
            lds[hi*256 + lo*16 + (j ^ lo)] = make_float2(v[2*h][j], v[2*h+1][j]);
        __syncthreads();
        const int slot = lo*16 + (hi ^ lo);
        #pragma unroll
        for (int k = 0; k < 16; ++k) {
            const float2 q = lds[k*256 + slot];
            v[2*h][k] = q.x; v[2*h+1][k] = q.y;
        }
    }

    // ---- phase 3: stages 8..11, p = 256k + t ----
    #pragma unroll
    for (int b = 0; b < 4; ++b) {
        const int s = 8 + b;
        float2 ws[16];
        #pragma unroll
        for (int k = 0; k < 16; ++k)
            ws[k] = *reinterpret_cast<const float2*>(W + ((size_t)s * LROW + k*256 + t) * 2);
        const int dl = 1 << b;
        #pragma unroll
        for (int g = 0; g < 16; g += 2*dl)
            #pragma unroll
            for (int m = 0; m < dl; ++m) {
                const int a = g + m, c = a + dl;
                #pragma unroll
                for (int r = 0; r < RPB; ++r) {
                    const float va = v[r][a], vb = v[r][c];
                    v[r][a] = ws[a].x * va + ws[a].y * vb;
                    v[r][c] = ws[c].x * vb + ws[c].y * va;
                }
            }
    }

    // ---- store: layout 3 => lane-consecutive dword stores, fully coalesced ----
    #pragma unroll
    for (int r = 0; r < RPB; ++r) {
        float* orow = out + (row0 + r) * LROW;
        #pragma unroll
        for (int k = 0; k < 16; ++k)
            orow[k*256 + t] = v[r][k];
    }
}

extern "C" void kernel_launch(void* const* d_in, const int* in_sizes, int n_in,
                              void* d_out, int out_size, void* d_ws, size_t ws_size,
                              hipStream_t stream) {
    const float* x = (const float*)d_in[0];   // (8192, 4096) fp32
    const float* W = (const float*)d_in[1];   // (12, 4096, 2) fp32
    float* out = (float*)d_out;               // (8192, 4096) fp32

    butterfly12_kernel<<<NBLK, 256, 0, stream>>>(x, W, out);
}

// Round 2
// 307.049 us; speedup vs baseline: 1.1779x; 1.1779x over previous
//
#include <hip/hip_runtime.h>

// Butterfly network: 12 stages over rows of 4096 fp32.
// y[p] <- W[s][p][0]*y[p] + W[s][p][1]*y[p^d],  d = 1<<s, s = 0..11
//
// One block (256 thr) processes RPB=4 rows entirely on-chip:
//   layout 1 (p = 16t+i)            -> stages 0..3 in registers
//   layout 2 (p = hi*256 + 16j+lo)  -> stages 4..7 in registers
//   layout 3 (p = 256k + t)         -> stages 8..11 in registers, coalesced store
//
// LDS is 32 KB (float2[4096] = row-PAIR packed); each transition runs twice
// (rows 0-1 then rows 2-3) with b64 LDS ops.
//
// __launch_bounds__(256, 4): VGPR cap 128 (NOT 5 -> cap ~102, which spilled
// v[4][16] to scratch in the previous round: WRITE_SIZE 131->394 MB, 48 VGPRs,
// VALUBusy halved). Kernel naturally needs ~88-110 VGPRs; at that count the
// HW can still co-resident 5 waves/SIMD (5 blocks/CU via 32 KB LDS).
//
// Swizzle: position (P2,P1,P0) row-pair lives at float2 index
//     A2 = P2*256 + P0*16 + (P1 ^ P0)
// All four access patterns are bank-uniform (4 lanes per bank-pair = the
// throughput minimum for wave64 b64 ops):
//   T1 write (thread = [P2|P1], iter i=P0): A2 = hi*256 + i*16 + (lo^i)
//   T1 read  (thread = [P2|P0], iter j=P1): A2 = hi*256 + lo*16 + (j^lo)
//   T2 write (thread = [P2|P0], iter j=P1): same addresses as T1 read
//                                           -> thread-private, no barrier
//   T2 read  (thread = [P1|P0], iter k=P2): A2 = k*256 + lo*16 + (hi^lo)
// XOR terms land in ADDRESSES only; register indices stay compile-time.

constexpr int LROW = 4096;
constexpr int RPB  = 4;     // rows per block
constexpr int NBLK = 8192 / RPB;

__global__ __launch_bounds__(256, 4)
void butterfly12_kernel(const float* __restrict__ x,
                        const float* __restrict__ W,
                        float* __restrict__ out)
{
    __shared__ float2 lds[LROW];   // 32 KB

    const int t  = threadIdx.x;
    const int hi = t >> 4;         // P2 in layouts 1,2 ; P1 in layout 3
    const int lo = t & 15;         // P1 in layout 1 ; P0 in layouts 2,3
    const size_t row0 = (size_t)blockIdx.x * RPB;

    float v[RPB][16];

    // ---- load: layout 1, p = 16t + i, 4 x float4 per row ----
    #pragma unroll
    for (int r = 0; r < RPB; ++r) {
        const float4* xr = reinterpret_cast<const float4*>(x + (row0 + r) * LROW);
        #pragma unroll
        for (int m = 0; m < 4; ++m) {
            const float4 q = xr[t * 4 + m];
            v[r][4*m+0] = q.x; v[r][4*m+1] = q.y;
            v[r][4*m+2] = q.z; v[r][4*m+3] = q.w;
        }
    }

    // ---- phase 1: stages 0..3, p = 16t + i ----
    #pragma unroll
    for (int b = 0; b < 4; ++b) {
        const int s = b;
        float2 ws[16];
        const float4* wq = reinterpret_cast<const float4*>(W + ((size_t)s * LROW + t * 16) * 2);
        #pragma unroll
        for (int m = 0; m < 8; ++m) {
            const float4 q = wq[m];
            ws[2*m]   = make_float2(q.x, q.y);
            ws[2*m+1] = make_float2(q.z, q.w);
        }
        const int dl = 1 << b;
        #pragma unroll
        for (int g = 0; g < 16; g += 2*dl)
            #pragma unroll
            for (int m = 0; m < dl; ++m) {
                const int a = g + m, c = a + dl;
                #pragma unroll
                for (int r = 0; r < RPB; ++r) {
                    const float va = v[r][a], vb = v[r][c];
                    v[r][a] = ws[a].x * va + ws[a].y * vb;
                    v[r][c] = ws[c].x * vb + ws[c].y * va;
                }
            }
    }

    // ---- transition 1 -> layout 2, row-pair at a time through 32 KB ----
    #pragma unroll
    for (int h = 0; h < 2; ++h) {
        if (h) __syncthreads();             // WAR: pair-0 reads done before overwrite
        #pragma unroll
        for (int i = 0; i < 16; ++i)
            lds[hi*256 + i*16 + (lo ^ i)] = make_float2(v[2*h][i], v[2*h+1][i]);
        __syncthreads();
        #pragma unroll
        for (int j = 0; j < 16; ++j) {
            const float2 q = lds[hi*256 + lo*16 + (j ^ lo)];
            v[2*h][j] = q.x; v[2*h+1][j] = q.y;
        }
    }

    // ---- phase 2: stages 4..7, p = hi*256 + 16j + lo ----
    #pragma unroll
    for (int b = 0; b < 4; ++b) {
        const int s = 4 + b;
        float2 ws[16];
        #pragma unroll
        for (int j = 0; j < 16; ++j)
            ws[j] = *reinterpret_cast<const float2*>(W + ((size_t)s * LROW + hi*256 + j*16 + lo) * 2);
        const int dl = 1 << b;
        #pragma unroll
        for (int g = 0; g < 16; g += 2*dl)
            #pragma unroll
            for (int m = 0; m < dl; ++m) {
                const int a = g + m, c = a + dl;
                #pragma unroll
                for (int r = 0; r < RPB; ++r) {
                    const float va = v[r][a], vb = v[r][c];
                    v[r][a] = ws[a].x * va + ws[a].y * vb;
                    v[r][c] = ws[c].x * vb + ws[c].y * va;
                }
            }
    }

    // ---- transition 2 -> layout 3, row-pair at a time ----
    // first write hits exactly the addresses this thread read in transition 1
    // (thread-private slot set => no barrier before it)
    #pragma unroll
    for (int h = 0; h < 2; ++h) {
        if (h) __syncthreads();
        #pragma unroll
        for (int j = 0; j < 16; ++j)
            lds[hi*256 + lo*16 + (j ^ lo)] = make_float2(v[2*h][j], v[2*h+1][j]);
        __syncthreads();
        const int slot = lo*16 + (hi ^ lo);
        #pragma unroll
        for (int k = 0; k < 16; ++k) {
            const float2 q = lds[k*256 + slot];
            v[2*h][k] = q.x; v[2*h+1][k] = q.y;
        }
    }

    // ---- phase 3: stages 8..11, p = 256k + t ----
    #pragma unroll
    for (int b = 0; b < 4; ++b) {
        const int s = 8 + b;
        float2 ws[16];
        #pragma unroll
        for (int k = 0; k < 16; ++k)
            ws[k] = *reinterpret_cast<const float2*>(W + ((size_t)s * LROW + k*256 + t) * 2);
        const int dl = 1 << b;
        #pragma unroll
        for (int g = 0; g < 16; g += 2*dl)
            #pragma unroll
            for (int m = 0; m < dl; ++m) {
                const int a = g + m, c = a + dl;
                #pragma unroll
                for (int r = 0; r < RPB; ++r) {
                    const float va = v[r][a], vb = v[r][c];
                    v[r][a] = ws[a].x * va + ws[a].y * vb;
                    v[r][c] = ws[c].x * vb + ws[c].y * va;
                }
            }
    }

    // ---- store: layout 3 => lane-consecutive dword stores, fully coalesced ----
    #pragma unroll
    for (int r = 0; r < RPB; ++r) {
        float* orow = out + (row0 + r) * LROW;
        #pragma unroll
        for (int k = 0; k < 16; ++k)
            orow[k*256 + t] = v[r][k];
    }
}

extern "C" void kernel_launch(void* const* d_in, const int* in_sizes, int n_in,
                              void* d_out, int out_size, void* d_ws, size_t ws_size,
                              hipStream_t stream) {
    const float* x = (const float*)d_in[0];   // (8192, 4096) fp32
    const float* W = (const float*)d_in[1];   // (12, 4096, 2) fp32
    float* out = (float*)d_out;               // (8192, 4096) fp32

    butterfly12_kernel<<<NBLK, 256, 0, stream>>>(x, W, out);
}